// Round 2
// baseline (228.540 us; speedup 1.0000x reference)
//
#include <hip/hip_runtime.h>
#include <hip/hip_bf16.h>

#define HW 2304          // 48*48
#define NB 8             // batch
#define NC 256           // input channels
#define HID 128          // heads*dim_head
#define DH 32            // dim_head
#define NH 4             // heads
#define SCALE 0.17677669529663687f   // 1/sqrt(32)
#define LOG2E 1.4426950408889634f
#define LN2   0.6931471805599453f

using bf16x8 = __attribute__((ext_vector_type(8))) short;
using f32x4  = __attribute__((ext_vector_type(4))) float;

__device__ __forceinline__ short f2bf(float f) {   // RNE float->bf16
    unsigned u = __float_as_uint(f);
    u += 0x7FFF + ((u >> 16) & 1);
    return (short)(u >> 16);
}
__device__ __forceinline__ unsigned pk2bf(float a, float b) {  // pack 2 bf16 (RNE)
    union { __hip_bfloat162 h; unsigned u; } cv;
    cv.h = __float22bfloat162_rn(float2{a, b});
    return cv.u;
}
__device__ __forceinline__ void gld16(const void* g, void* l) {  // 16B global->LDS DMA
    __builtin_amdgcn_global_load_lds(
        (const __attribute__((address_space(1))) unsigned*)g,
        (__attribute__((address_space(3))) unsigned*)l, 16, 0, 0);
}

// ---------------------------------------------------------------------------
// Fused pre-pass. z<8: x [b][256][2304] fp32 -> Xt [b][2304][256] bf16.
// z==8: weight fp32->bf16 conversion + zero the E/ticket words.
// ---------------------------------------------------------------------------
__global__ __launch_bounds__(256)
void prep(const float* __restrict__ x, const float* __restrict__ wq,
          const float* __restrict__ wo, short* __restrict__ Xt,
          short* __restrict__ Wq, short* __restrict__ Wo, float* __restrict__ wsz)
{
    if (blockIdx.z == 8) {
        const int bid = blockIdx.x + 72 * blockIdx.y;
        if (bid == 0 && threadIdx.x == 0) { wsz[0] = 0.f; ((int*)wsz)[1] = 0; }
        const int i = bid * 256 + threadIdx.x;
        if (i < 384 * 256) Wq[i] = f2bf(wq[i]);
        if (i < 256 * 128) Wo[i] = f2bf(wo[i]);
        return;
    }
    __shared__ float T[32][33];
    const int b = blockIdx.z, c0 = blockIdx.y * 32, s0 = blockIdx.x * 32;
    const int ts = threadIdx.x & 31, tc = threadIdx.x >> 5;
    #pragma unroll
    for (int cc = tc; cc < 32; cc += 8)
        T[cc][ts] = x[((size_t)b * NC + c0 + cc) * HW + s0 + ts];
    __syncthreads();
    const int tcc = threadIdx.x & 31, tss = threadIdx.x >> 5;
    #pragma unroll
    for (int ss = tss; ss < 32; ss += 8)
        Xt[((size_t)b * HW + s0 + ss) * NC + c0 + tcc] = f2bf(T[tcc][ss]);
}

// ---------------------------------------------------------------------------
// MFMA 1x1-conv GEMM with gld16-staged, double-buffered LDS tiles (m97-style:
// one barrier per 32-K chunk = DMA drain; MFMA stream never waits on VMEM).
// Tile M64 x N128. LDS per buffer: A 64x32 (4KB, 4 deposit ops) + B 128x32
// (8KB, 8 ops); 12 ops spread 3-per-wave. Deposit lane L holds global column
// block (L&3)^(rL&3) (XOR swizzle); frag read offset (quad^(n16&3))*16.
// Epilogue (unchanged): Q(xSCALE*LOG2E)/K(pair-permuted) [bh][s][dh],
// V [bh][dh][s]; else fp32 out + ticketed energy store.
// ---------------------------------------------------------------------------
template<int KD, bool QKV>
__global__ __launch_bounds__(256, 4)
void conv_mfma(const short* __restrict__ A, const short* __restrict__ Bt,
               const float* __restrict__ bias, float* __restrict__ out0,
               short* __restrict__ Qb, short* __restrict__ Kb,
               short* __restrict__ Vb, float* __restrict__ E,
               int* __restrict__ ticket, int nblocks, float* __restrict__ edst)
{
    const int b  = blockIdx.z;
    const int bm = blockIdx.y * 64;
    const int bn = blockIdx.x * 128;
    const int t  = threadIdx.x;
    const int w  = t >> 6, lane = t & 63;
    const int n16 = lane & 15, quad = lane >> 4;

    __shared__ __align__(16) char csm[24576];   // 2 x (A 4KB | B 8KB)
    __shared__ float red[4];

    // deposit-side global lane addresses
    const int rL = lane >> 2, cswz = (lane & 3) ^ (rL & 3);
    const char* agl = (const char*)(A  + (size_t)(bm + rL) * KD + cswz * 8);
    const char* bgl = (const char*)(Bt + ((size_t)b * HW + bn + rL) * KD + cswz * 8);

    auto issue = [&](int kc, int pbuf) {
        char* base = csm + pbuf * 12288;
        if (w == 0) {
            gld16(agl + (size_t)(0 * 16 * KD + kc) * 2, base + 0 * 1024);
            gld16(agl + (size_t)(1 * 16 * KD + kc) * 2, base + 1 * 1024);
            gld16(bgl + (size_t)(0 * 16 * KD + kc) * 2, base + 4096 + 0 * 1024);
        } else if (w == 1) {
            gld16(agl + (size_t)(2 * 16 * KD + kc) * 2, base + 2 * 1024);
            gld16(agl + (size_t)(3 * 16 * KD + kc) * 2, base + 3 * 1024);
            gld16(bgl + (size_t)(1 * 16 * KD + kc) * 2, base + 4096 + 1 * 1024);
        } else if (w == 2) {
            gld16(bgl + (size_t)(2 * 16 * KD + kc) * 2, base + 4096 + 2 * 1024);
            gld16(bgl + (size_t)(3 * 16 * KD + kc) * 2, base + 4096 + 3 * 1024);
            gld16(bgl + (size_t)(4 * 16 * KD + kc) * 2, base + 4096 + 4 * 1024);
        } else {
            gld16(bgl + (size_t)(5 * 16 * KD + kc) * 2, base + 4096 + 5 * 1024);
            gld16(bgl + (size_t)(6 * 16 * KD + kc) * 2, base + 4096 + 6 * 1024);
            gld16(bgl + (size_t)(7 * 16 * KD + kc) * 2, base + 4096 + 7 * 1024);
        }
    };

    f32x4 acc[4][2] = {};
    const int rsw = (quad ^ (n16 & 3)) * 16;    // frag-read swizzle (bytes)
    constexpr int NI = KD / 32;

    issue(0, 0);
    for (int ki = 0; ki < NI; ++ki) {
        const int p = ki & 1;
        __syncthreads();                        // vmcnt(0) drain: chunk ki landed
        if (ki + 1 < NI) issue((ki + 1) * 32, p ^ 1);

        const char* Ap = csm + p * 12288;
        const char* Bp = Ap + 4096;
        bf16x8 am[4], bq[2];
        #pragma unroll
        for (int tm = 0; tm < 4; ++tm)
            am[tm] = *(const bf16x8*)(Ap + tm * 1024 + n16 * 64 + rsw);
        #pragma unroll
        for (int j = 0; j < 2; ++j)
            bq[j] = *(const bf16x8*)(Bp + (w * 2 + j) * 1024 + n16 * 64 + rsw);
        #pragma unroll
        for (int tm = 0; tm < 4; ++tm)
            #pragma unroll
            for (int j = 0; j < 2; ++j)
                acc[tm][j] = __builtin_amdgcn_mfma_f32_16x16x32_bf16(am[tm], bq[j], acc[tm][j], 0, 0, 0);
    }

    float e = 0.f;
    #pragma unroll
    for (int tm = 0; tm < 4; ++tm) {
        const int o0 = bm + tm * 16 + quad * 4;
        const float4 bb = *(const float4*)(bias + o0);
        #pragma unroll
        for (int j = 0; j < 2; ++j) {
            const int s = bn + (w * 2 + j) * 16 + n16;
            float v[4] = {acc[tm][j][0] + bb.x, acc[tm][j][1] + bb.y,
                          acc[tm][j][2] + bb.z, acc[tm][j][3] + bb.w};
            e -= 0.5f * (v[0]*v[0] + v[1]*v[1] + v[2]*v[2] + v[3]*v[3]);
            if (QKV) {
                if (o0 < HID) {                       // Q: scaled by SCALE*log2e
                    const int h = o0 >> 5, dh0 = o0 & 31;
                    const float qs = SCALE * LOG2E;
                    short4 pk = {f2bf(v[0]*qs), f2bf(v[1]*qs),
                                 f2bf(v[2]*qs), f2bf(v[3]*qs)};
                    *(short4*)(Qb + ((size_t)(b * NH + h) * HW + s) * DH + dh0) = pk;
                } else if (o0 < 2 * HID) {            // K: pair-permuted rows
                    const int c = o0 - HID, h = c >> 5, dh0 = c & 31;
                    const int g = s & 31;
                    const int sp = (s & ~31) | ((g & 1) << 4) | (g >> 1);
                    short4 pk = {f2bf(v[0]), f2bf(v[1]), f2bf(v[2]), f2bf(v[3])};
                    *(short4*)(Kb + ((size_t)(b * NH + h) * HW + sp) * DH + dh0) = pk;
                } else {                              // V: [bh][dh][s]
                    const int c = o0 - 2 * HID, h = c >> 5, dh0 = c & 31;
                    #pragma unroll
                    for (int r = 0; r < 4; ++r)
                        Vb[((size_t)(b * NH + h) * DH + dh0 + r) * HW + s] = f2bf(v[r]);
                }
            } else {
                #pragma unroll
                for (int r = 0; r < 4; ++r)
                    out0[((size_t)b * NC + o0 + r) * HW + s] = v[r];
            }
        }
    }

    #pragma unroll
    for (int off = 32; off > 0; off >>= 1) e += __shfl_down(e, off);
    if (lane == 0) red[w] = e;
    __syncthreads();
    if (t == 0) {
        atomicAdd(E, red[0] + red[1] + red[2] + red[3]);
        if (!QKV) {
            __threadfence();
            const int prev = atomicAdd(ticket, 1);
            if (prev == nblocks - 1) {
                __threadfence();
                edst[0] = atomicAdd(E, 0.f);
            }
        }
    }
}

// ---------------------------------------------------------------------------
// Flash attention v8 = v7 with 16 queries per wave (was 32) for 2x occupancy.
// Grid 36 x 32: block = 64 queries x 4 waves; wave owns 16 queries (1 qg),
// walks all 2304 keys in 36 iterations x 64 keys (2 chunks of 32). Shared K/V
// pair buffers (2 x 8KB, double-buffered), DMA'd by all 256 threads (2 gld16
// each, XOR swizzle, identical to v7); ONE barrier per 64 keys. m=0 fixed
// shift, raw v_exp_f32. Per-wave P tile (16 rows x 40 shorts per chunk).
// 4608 waves total -> ~18 waves/CU ceiling (v7: 9). attT: bf16 [b][s][hid].
// ---------------------------------------------------------------------------
__global__ __launch_bounds__(256)
void flash7(const short* __restrict__ Qb, const short* __restrict__ Kb,
            const short* __restrict__ Vb, short* __restrict__ attT,
            float* __restrict__ E)
{
    __shared__ __align__(16) char smem[16384 + 4 * 2560];
    // [0,16384): KV buffers: parity p at p*8192, chunk ca at +ca*4096
    //            (4KB: K keys0-15 | keys16-31 | V dh0-15 | dh16-31, 1KB each)
    // [16384,+): per-wave P: wave w at +w*2560, chunk ca at +ca*1280
    //            (16 rows x 40 shorts)

    const int bh   = blockIdx.y;
    const int w    = threadIdx.x >> 6;
    const int lane = threadIdx.x & 63;
    const int n16  = lane & 15, quad = lane >> 4;
    const int qb   = blockIdx.x * 64 + w * 16;

    const bf16x8 aq = *(const bf16x8*)(Qb + ((size_t)bh * HW + qb + n16) * DH + quad * 8);

    // DMA role: waves 0,1 -> K halves; waves 2,3 -> V halves.
    const int rL = lane >> 2, cL = (lane & 3) ^ (rL & 3);
    const char* gbase; size_t gstep;
    if (w < 2) {
        gbase = (const char*)(Kb + (size_t)bh * HW * DH) + ((w & 1) * 16 + rL) * 64 + cL * 16;
        gstep = 2048;                      // 32 keys * 64 B
    } else {
        gbase = (const char*)(Vb + (size_t)bh * DH * HW)
              + (size_t)((w & 1) * 16 + rL) * (HW * 2) + cL * 16;
        gstep = 64;                        // 32 keys * 2 B per dh-row
    }

    // preload iteration 0 (chunks 0,1) -> parity 0
    gld16(gbase,         smem + 0    + w * 1024);
    gld16(gbase + gstep, smem + 4096 + w * 1024);

    f32x4 acc[2] = {};
    float ls[4] = {}, ts[4] = {};
    const int swz = (quad ^ (n16 & 3)) * 8;   // frag-read XOR swizzle (shorts)
    short* Pbase = (short*)(smem + 16384) + w * 1280;   // 1280 shorts = 2560 B

    for (int it = 0; it < 36; ++it) {
        const int p = it & 1;
        __syncthreads();                   // pair `it` landed; pair it-1 fully read
        if (it + 1 < 36) {
            const size_t g0 = (size_t)(2 * it + 2) * gstep;
            gld16(gbase + g0,         smem + (p ^ 1) * 8192 + 0    + w * 1024);
            gld16(gbase + g0 + gstep, smem + (p ^ 1) * 8192 + 4096 + w * 1024);
        }

        #pragma unroll
        for (int ca = 0; ca < 2; ++ca) {
            const short* kb = (const short*)(smem + p * 8192 + ca * 4096);
            short* Ps = Pbase + ca * 640;            // 640 shorts = 1280 B
            unsigned* P32 = (unsigned*)Ps;

            const bf16x8 bk0 = *(const bf16x8*)(kb + n16 * 32 + swz);          // keys(perm) 0-15
            const bf16x8 bk1 = *(const bf16x8*)(kb + 512  + n16 * 32 + swz);   // keys(perm) 16-31
            const bf16x8 bv0 = *(const bf16x8*)(kb + 1024 + n16 * 32 + swz);   // dh 0-15
            const bf16x8 bv1 = *(const bf16x8*)(kb + 1536 + n16 * 32 + swz);   // dh 16-31

            f32x4 z = {};
            const f32x4 s0 = __builtin_amdgcn_mfma_f32_16x16x32_bf16(aq, bk0, z, 0, 0, 0);
            const f32x4 s1 = __builtin_amdgcn_mfma_f32_16x16x32_bf16(aq, bk1, z, 0, 0, 0);
            #pragma unroll
            for (int r = 0; r < 4; ++r) {
                const float p0 = __builtin_amdgcn_exp2f(s0[r]);   // key 2*n16
                const float p1 = __builtin_amdgcn_exp2f(s1[r]);   // key 2*n16+1
                ls[r] += p0 + p1;
                ts[r] += p0 * s0[r] + p1 * s1[r];
                P32[(quad * 4 + r) * 20 + n16] = pk2bf(p0, p1);
            }
            const bf16x8 pa = *(const bf16x8*)(Ps + n16 * 40 + quad * 8);
            acc[0] = __builtin_amdgcn_mfma_f32_16x16x32_bf16(pa, bv0, acc[0], 0, 0, 0);
            acc[1] = __builtin_amdgcn_mfma_f32_16x16x32_bf16(pa, bv1, acc[1], 0, 0, 0);
        }
    }

    // reduce ls/ts across the 16 lanes (key dim) of each quad group
    #pragma unroll
    for (int m = 1; m < 16; m <<= 1)
        #pragma unroll
        for (int r = 0; r < 4; ++r) {
            ls[r] += __shfl_xor(ls[r], m);
            ts[r] += __shfl_xor(ts[r], m);
        }

    const int bb = bh >> 2, h = bh & 3;
    float e = 0.f;
    #pragma unroll
    for (int r = 0; r < 4; ++r) {
        const int q = qb + quad * 4 + r;
        const float L = ls[r];
        const float invl = 1.f / L;
        short* ap = attT + ((size_t)bb * HW + q) * HID + h * 32;
        ap[n16]      = f2bf(acc[0][r] * invl);
        ap[n16 + 16] = f2bf(acc[1][r] * invl);
        e += (LN2 * ts[r]) * invl - __logf(L);
    }
    e = (n16 == 0) ? e : 0.f;
    e += __shfl_xor(e, 16);
    e += __shfl_xor(e, 32);
    if (lane == 0) atomicAdd(E, e);
}

// ---------------------------------------------------------------------------
extern "C" void kernel_launch(void* const* d_in, const int* in_sizes, int n_in,
                              void* d_out, int out_size, void* d_ws, size_t ws_size,
                              hipStream_t stream) {
    const float* x     = (const float*)d_in[0];
    const float* w_qkv = (const float*)d_in[1];
    const float* b_qkv = (const float*)d_in[2];
    const float* w_out = (const float*)d_in[3];
    const float* b_out = (const float*)d_in[4];
    float* out = (float*)d_out;

    float* wsf    = (float*)d_ws;
    float* E      = wsf;                               // [0] energy accumulator
    int*   ticket = (int*)d_ws + 1;                    // [1] conv2 ticket
    short* Xt   = (short*)(wsf + 16);                  // bf16 [b][s][c]
    short* Wq   = Xt + (size_t)NB * HW * NC;           // bf16 [384][256]
    short* Wo   = Wq + 384 * 256;                      // bf16 [256][128]
    short* Qb   = Wo + 256 * 128;                      // bf16 [bh][s][dh] (xSCALE*log2e)
    short* Kb   = Qb + (size_t)NB * NH * HW * DH;      // bf16 [bh][s'][dh], pair-permuted
    short* Vb   = Kb + (size_t)NB * NH * HW * DH;      // bf16 [bh][dh][s]
    short* attT = Vb + (size_t)NB * NH * HW * DH;      // bf16 [b][s][hid]

    prep<<<dim3(HW / 32, NC / 32, NB + 1), 256, 0, stream>>>(
        x, w_qkv, w_out, Xt, Wq, Wo, wsf);
    conv_mfma<NC, true><<<dim3(18, 6, NB), 256, 0, stream>>>(
        Wq, Xt, b_qkv, nullptr, Qb, Kb, Vb, E, nullptr, 0, nullptr);
    flash7<<<dim3(HW / 64, NB * NH), 256, 0, stream>>>(
        Qb, Kb, Vb, attT, E);
    conv_mfma<HID, false><<<dim3(18, 4, NB), 256, 0, stream>>>(
        Wo, attT, b_out, out, nullptr, nullptr, nullptr, E,
        ticket, 18 * 4 * NB, out + (size_t)NB * NC * HW);
}

// Round 3
// 208.090 us; speedup vs baseline: 1.0983x; 1.0983x over previous
//
#include <hip/hip_runtime.h>
#include <hip/hip_bf16.h>

#define HW 2304          // 48*48
#define NB 8             // batch
#define NC 256           // input channels
#define HID 128          // heads*dim_head
#define DH 32            // dim_head
#define NH 4             // heads
#define SCALE 0.17677669529663687f   // 1/sqrt(32)
#define LOG2E 1.4426950408889634f
#define LN2   0.6931471805599453f

using bf16x8 = __attribute__((ext_vector_type(8))) short;
using f32x4  = __attribute__((ext_vector_type(4))) float;

__device__ __forceinline__ short f2bf(float f) {   // RNE float->bf16
    unsigned u = __float_as_uint(f);
    u += 0x7FFF + ((u >> 16) & 1);
    return (short)(u >> 16);
}
__device__ __forceinline__ unsigned pk2bf(float a, float b) {  // pack 2 bf16 (RNE)
    union { __hip_bfloat162 h; unsigned u; } cv;
    cv.h = __float22bfloat162_rn(float2{a, b});
    return cv.u;
}
__device__ __forceinline__ void gld16(const void* g, void* l) {  // 16B global->LDS DMA
    __builtin_amdgcn_global_load_lds(
        (const __attribute__((address_space(1))) unsigned*)g,
        (__attribute__((address_space(3))) unsigned*)l, 16, 0, 0);
}

// ---------------------------------------------------------------------------
// Fused pre-pass. z<8: x [b][256][2304] fp32 -> Xt [b][2304][256] bf16.
// z==8: weight fp32->bf16 conversion + zero the E/ticket words.
// ---------------------------------------------------------------------------
__global__ __launch_bounds__(256)
void prep(const float* __restrict__ x, const float* __restrict__ wq,
          const float* __restrict__ wo, short* __restrict__ Xt,
          short* __restrict__ Wq, short* __restrict__ Wo, float* __restrict__ wsz)
{
    if (blockIdx.z == 8) {
        const int bid = blockIdx.x + 72 * blockIdx.y;
        if (bid == 0 && threadIdx.x == 0) { wsz[0] = 0.f; ((int*)wsz)[1] = 0; }
        const int i = bid * 256 + threadIdx.x;
        if (i < 384 * 256) Wq[i] = f2bf(wq[i]);
        if (i < 256 * 128) Wo[i] = f2bf(wo[i]);
        return;
    }
    __shared__ float T[32][33];
    const int b = blockIdx.z, c0 = blockIdx.y * 32, s0 = blockIdx.x * 32;
    const int ts = threadIdx.x & 31, tc = threadIdx.x >> 5;
    #pragma unroll
    for (int cc = tc; cc < 32; cc += 8)
        T[cc][ts] = x[((size_t)b * NC + c0 + cc) * HW + s0 + ts];
    __syncthreads();
    const int tcc = threadIdx.x & 31, tss = threadIdx.x >> 5;
    #pragma unroll
    for (int ss = tss; ss < 32; ss += 8)
        Xt[((size_t)b * HW + s0 + ss) * NC + c0 + tcc] = f2bf(T[tcc][ss]);
}

// ---------------------------------------------------------------------------
// MFMA 1x1-conv GEMM with gld16-staged, double-buffered LDS tiles (m97-style:
// one barrier per 32-K chunk = DMA drain; MFMA stream never waits on VMEM).
// Tile M64 x N128. LDS per buffer: A 64x32 (4KB, 4 deposit ops) + B 128x32
// (8KB, 8 ops); 12 ops spread 3-per-wave. Deposit lane L holds global column
// block (L&3)^(rL&3) (XOR swizzle); frag read offset (quad^(n16&3))*16.
// Epilogue: Q(xSCALE*LOG2E) [bh][s][dh]; K permuted with sigma(g) =
// ((g&4)<<2)|((g>>3)<<2)|(g&3) within each 32-key group so flash9's swapped
// QK^T lands P directly in PV B-frag layout; V [bh][dh][s]; else fp32 out +
// ticketed energy store.
// ---------------------------------------------------------------------------
template<int KD, bool QKV>
__global__ __launch_bounds__(256, 4)
void conv_mfma(const short* __restrict__ A, const short* __restrict__ Bt,
               const float* __restrict__ bias, float* __restrict__ out0,
               short* __restrict__ Qb, short* __restrict__ Kb,
               short* __restrict__ Vb, float* __restrict__ E,
               int* __restrict__ ticket, int nblocks, float* __restrict__ edst)
{
    const int b  = blockIdx.z;
    const int bm = blockIdx.y * 64;
    const int bn = blockIdx.x * 128;
    const int t  = threadIdx.x;
    const int w  = t >> 6, lane = t & 63;
    const int n16 = lane & 15, quad = lane >> 4;

    __shared__ __align__(16) char csm[24576];   // 2 x (A 4KB | B 8KB)
    __shared__ float red[4];

    // deposit-side global lane addresses
    const int rL = lane >> 2, cswz = (lane & 3) ^ (rL & 3);
    const char* agl = (const char*)(A  + (size_t)(bm + rL) * KD + cswz * 8);
    const char* bgl = (const char*)(Bt + ((size_t)b * HW + bn + rL) * KD + cswz * 8);

    auto issue = [&](int kc, int pbuf) {
        char* base = csm + pbuf * 12288;
        if (w == 0) {
            gld16(agl + (size_t)(0 * 16 * KD + kc) * 2, base + 0 * 1024);
            gld16(agl + (size_t)(1 * 16 * KD + kc) * 2, base + 1 * 1024);
            gld16(bgl + (size_t)(0 * 16 * KD + kc) * 2, base + 4096 + 0 * 1024);
        } else if (w == 1) {
            gld16(agl + (size_t)(2 * 16 * KD + kc) * 2, base + 2 * 1024);
            gld16(agl + (size_t)(3 * 16 * KD + kc) * 2, base + 3 * 1024);
            gld16(bgl + (size_t)(1 * 16 * KD + kc) * 2, base + 4096 + 1 * 1024);
        } else if (w == 2) {
            gld16(bgl + (size_t)(2 * 16 * KD + kc) * 2, base + 4096 + 2 * 1024);
            gld16(bgl + (size_t)(3 * 16 * KD + kc) * 2, base + 4096 + 3 * 1024);
            gld16(bgl + (size_t)(4 * 16 * KD + kc) * 2, base + 4096 + 4 * 1024);
        } else {
            gld16(bgl + (size_t)(5 * 16 * KD + kc) * 2, base + 4096 + 5 * 1024);
            gld16(bgl + (size_t)(6 * 16 * KD + kc) * 2, base + 4096 + 6 * 1024);
            gld16(bgl + (size_t)(7 * 16 * KD + kc) * 2, base + 4096 + 7 * 1024);
        }
    };

    f32x4 acc[4][2] = {};
    const int rsw = (quad ^ (n16 & 3)) * 16;    // frag-read swizzle (bytes)
    constexpr int NI = KD / 32;

    issue(0, 0);
    for (int ki = 0; ki < NI; ++ki) {
        const int p = ki & 1;
        __syncthreads();                        // vmcnt(0) drain: chunk ki landed
        if (ki + 1 < NI) issue((ki + 1) * 32, p ^ 1);

        const char* Ap = csm + p * 12288;
        const char* Bp = Ap + 4096;
        bf16x8 am[4], bq[2];
        #pragma unroll
        for (int tm = 0; tm < 4; ++tm)
            am[tm] = *(const bf16x8*)(Ap + tm * 1024 + n16 * 64 + rsw);
        #pragma unroll
        for (int j = 0; j < 2; ++j)
            bq[j] = *(const bf16x8*)(Bp + (w * 2 + j) * 1024 + n16 * 64 + rsw);
        #pragma unroll
        for (int tm = 0; tm < 4; ++tm)
            #pragma unroll
            for (int j = 0; j < 2; ++j)
                acc[tm][j] = __builtin_amdgcn_mfma_f32_16x16x32_bf16(am[tm], bq[j], acc[tm][j], 0, 0, 0);
    }

    float e = 0.f;
    #pragma unroll
    for (int tm = 0; tm < 4; ++tm) {
        const int o0 = bm + tm * 16 + quad * 4;
        const float4 bb = *(const float4*)(bias + o0);
        #pragma unroll
        for (int j = 0; j < 2; ++j) {
            const int s = bn + (w * 2 + j) * 16 + n16;
            float v[4] = {acc[tm][j][0] + bb.x, acc[tm][j][1] + bb.y,
                          acc[tm][j][2] + bb.z, acc[tm][j][3] + bb.w};
            e -= 0.5f * (v[0]*v[0] + v[1]*v[1] + v[2]*v[2] + v[3]*v[3]);
            if (QKV) {
                if (o0 < HID) {                       // Q: scaled by SCALE*log2e
                    const int h = o0 >> 5, dh0 = o0 & 31;
                    const float qs = SCALE * LOG2E;
                    short4 pk = {f2bf(v[0]*qs), f2bf(v[1]*qs),
                                 f2bf(v[2]*qs), f2bf(v[3]*qs)};
                    *(short4*)(Qb + ((size_t)(b * NH + h) * HW + s) * DH + dh0) = pk;
                } else if (o0 < 2 * HID) {            // K: sigma-permuted rows
                    const int c = o0 - HID, h = c >> 5, dh0 = c & 31;
                    const int g = s & 31;
                    const int sp = (s & ~31) | ((g & 4) << 2) | ((g >> 3) << 2) | (g & 3);
                    short4 pk = {f2bf(v[0]), f2bf(v[1]), f2bf(v[2]), f2bf(v[3])};
                    *(short4*)(Kb + ((size_t)(b * NH + h) * HW + sp) * DH + dh0) = pk;
                } else {                              // V: [bh][dh][s]
                    const int c = o0 - 2 * HID, h = c >> 5, dh0 = c & 31;
                    #pragma unroll
                    for (int r = 0; r < 4; ++r)
                        Vb[((size_t)(b * NH + h) * DH + dh0 + r) * HW + s] = f2bf(v[r]);
                }
            } else {
                #pragma unroll
                for (int r = 0; r < 4; ++r)
                    out0[((size_t)b * NC + o0 + r) * HW + s] = v[r];
            }
        }
    }

    #pragma unroll
    for (int off = 32; off > 0; off >>= 1) e += __shfl_down(e, off);
    if (lane == 0) red[w] = e;
    __syncthreads();
    if (t == 0) {
        atomicAdd(E, red[0] + red[1] + red[2] + red[3]);
        if (!QKV) {
            __threadfence();
            const int prev = atomicAdd(ticket, 1);
            if (prev == nblocks - 1) {
                __threadfence();
                edst[0] = atomicAdd(E, 0.f);
            }
        }
    }
}

// ---------------------------------------------------------------------------
// Flash attention v9 = v7 grid (32q/wave, 18x32) with SWAPPED-OPERAND MFMAs:
// S^T = mfma(K,Q) puts S[key=quad*4+r][q=n16] in registers; with the conv-side
// sigma K-permutation, exp(S) packs (4x cvt_pk) DIRECTLY into the PV B-frag
// (keys quad*8+j), and O^T = mfma(V,P) gives O[q=n16][dh=quad*4+r(+16)].
// -> NO P tile in LDS, no P bank conflicts, no lgkmcnt round-trip; ls/ts are
// lane-local scalars per qg (quad-reduce at end); attT store = 2x short4/qg.
// K/V DMA + double-buffer + 1 barrier per 64 keys identical to v7.
// ---------------------------------------------------------------------------
__global__ __launch_bounds__(256)
void flash9(const short* __restrict__ Qb, const short* __restrict__ Kb,
            const short* __restrict__ Vb, short* __restrict__ attT,
            float* __restrict__ E)
{
    __shared__ __align__(16) char smem[16384];
    // KV buffers: parity p at p*8192, chunk ca at +ca*4096
    // (4KB: K keypos0-15 | keypos16-31 | V dh0-15 | dh16-31, 1KB each)

    const int bh   = blockIdx.y;
    const int w    = threadIdx.x >> 6;
    const int lane = threadIdx.x & 63;
    const int n16  = lane & 15, quad = lane >> 4;
    const int qb   = blockIdx.x * 128 + w * 32;

    bf16x8 aq[2];
    #pragma unroll
    for (int qg = 0; qg < 2; ++qg)
        aq[qg] = *(const bf16x8*)(Qb + ((size_t)bh * HW + qb + qg * 16 + n16) * DH + quad * 8);

    // DMA role: waves 0,1 -> K halves; waves 2,3 -> V halves.
    const int rL = lane >> 2, cL = (lane & 3) ^ (rL & 3);
    const char* gbase; size_t gstep;
    if (w < 2) {
        gbase = (const char*)(Kb + (size_t)bh * HW * DH) + ((w & 1) * 16 + rL) * 64 + cL * 16;
        gstep = 2048;                      // 32 keys * 64 B
    } else {
        gbase = (const char*)(Vb + (size_t)bh * DH * HW)
              + (size_t)((w & 1) * 16 + rL) * (HW * 2) + cL * 16;
        gstep = 64;                        // 32 keys * 2 B per dh-row
    }

    // preload iteration 0 (chunks 0,1) -> parity 0
    gld16(gbase,         smem + 0    + w * 1024);
    gld16(gbase + gstep, smem + 4096 + w * 1024);

    f32x4 acc[2][2] = {};                     // [qg][dh-half]: O[q=n16][dh]
    float ls[2] = {}, ts[2] = {};             // lane-local partials, query (qg,n16)
    const int swz = (quad ^ (n16 & 3)) * 8;   // frag-read XOR swizzle (shorts)

    for (int it = 0; it < 36; ++it) {
        const int p = it & 1;
        __syncthreads();                   // pair `it` landed; pair it-1 fully read
        if (it + 1 < 36) {
            const size_t g0 = (size_t)(2 * it + 2) * gstep;
            gld16(gbase + g0,         smem + (p ^ 1) * 8192 + 0    + w * 1024);
            gld16(gbase + g0 + gstep, smem + (p ^ 1) * 8192 + 4096 + w * 1024);
        }

        #pragma unroll
        for (int ca = 0; ca < 2; ++ca) {
            const short* kb = (const short*)(smem + p * 8192 + ca * 4096);

            const bf16x8 bk0 = *(const bf16x8*)(kb + n16 * 32 + swz);          // keypos 0-15
            const bf16x8 bk1 = *(const bf16x8*)(kb + 512  + n16 * 32 + swz);   // keypos 16-31
            const bf16x8 bv0 = *(const bf16x8*)(kb + 1024 + n16 * 32 + swz);   // dh 0-15
            const bf16x8 bv1 = *(const bf16x8*)(kb + 1536 + n16 * 32 + swz);   // dh 16-31

            #pragma unroll
            for (int qg = 0; qg < 2; ++qg) {
                f32x4 z = {};
                // swapped: C row = key position, col = query n16
                const f32x4 s0 = __builtin_amdgcn_mfma_f32_16x16x32_bf16(bk0, aq[qg], z, 0, 0, 0);
                const f32x4 s1 = __builtin_amdgcn_mfma_f32_16x16x32_bf16(bk1, aq[qg], z, 0, 0, 0);
                float e0[4], e1[4];
                #pragma unroll
                for (int r = 0; r < 4; ++r) {
                    e0[r] = __builtin_amdgcn_exp2f(s0[r]);   // key quad*8+r
                    e1[r] = __builtin_amdgcn_exp2f(s1[r]);   // key quad*8+4+r
                }
                ls[qg] += (e0[0] + e0[1]) + (e0[2] + e0[3])
                        + (e1[0] + e1[1]) + (e1[2] + e1[3]);
                ts[qg] += (e0[0]*s0[0] + e0[1]*s0[1]) + (e0[2]*s0[2] + e0[3]*s0[3])
                        + (e1[0]*s1[0] + e1[1]*s1[1]) + (e1[2]*s1[2] + e1[3]*s1[3]);
                union { bf16x8 v; unsigned u[4]; } pa;
                pa.u[0] = pk2bf(e0[0], e0[1]);
                pa.u[1] = pk2bf(e0[2], e0[3]);
                pa.u[2] = pk2bf(e1[0], e1[1]);
                pa.u[3] = pk2bf(e1[2], e1[3]);
                // swapped PV: C row = dh part, col = query n16
                acc[qg][0] = __builtin_amdgcn_mfma_f32_16x16x32_bf16(bv0, pa.v, acc[qg][0], 0, 0, 0);
                acc[qg][1] = __builtin_amdgcn_mfma_f32_16x16x32_bf16(bv1, pa.v, acc[qg][1], 0, 0, 0);
            }
        }
    }

    // reduce ls/ts across the 4 quad lanes (key blocks) of each query
    #pragma unroll
    for (int qg = 0; qg < 2; ++qg) {
        ls[qg] += __shfl_xor(ls[qg], 16);
        ls[qg] += __shfl_xor(ls[qg], 32);
        ts[qg] += __shfl_xor(ts[qg], 16);
        ts[qg] += __shfl_xor(ts[qg], 32);
    }

    const int bb = bh >> 2, h = bh & 3;
    float e = 0.f;
    #pragma unroll
    for (int qg = 0; qg < 2; ++qg) {
        const int q = qb + qg * 16 + n16;
        const float L = ls[qg];
        const float invl = 1.f / L;
        short* ap = attT + ((size_t)bb * HW + q) * HID + h * 32;
        short4 pk0 = {f2bf(acc[qg][0][0] * invl), f2bf(acc[qg][0][1] * invl),
                      f2bf(acc[qg][0][2] * invl), f2bf(acc[qg][0][3] * invl)};
        short4 pk1 = {f2bf(acc[qg][1][0] * invl), f2bf(acc[qg][1][1] * invl),
                      f2bf(acc[qg][1][2] * invl), f2bf(acc[qg][1][3] * invl)};
        *(short4*)(ap + quad * 4)      = pk0;   // dh quad*4 .. +3
        *(short4*)(ap + 16 + quad * 4) = pk1;   // dh 16+quad*4 .. +3
        if (quad == 0) e += (LN2 * ts[qg]) * invl - __logf(L);
    }
    #pragma unroll
    for (int m = 1; m < 64; m <<= 1) e += __shfl_xor(e, m);
    if (lane == 0) atomicAdd(E, e);
}

// ---------------------------------------------------------------------------
extern "C" void kernel_launch(void* const* d_in, const int* in_sizes, int n_in,
                              void* d_out, int out_size, void* d_ws, size_t ws_size,
                              hipStream_t stream) {
    const float* x     = (const float*)d_in[0];
    const float* w_qkv = (const float*)d_in[1];
    const float* b_qkv = (const float*)d_in[2];
    const float* w_out = (const float*)d_in[3];
    const float* b_out = (const float*)d_in[4];
    float* out = (float*)d_out;

    float* wsf    = (float*)d_ws;
    float* E      = wsf;                               // [0] energy accumulator
    int*   ticket = (int*)d_ws + 1;                    // [1] conv2 ticket
    short* Xt   = (short*)(wsf + 16);                  // bf16 [b][s][c]
    short* Wq   = Xt + (size_t)NB * HW * NC;           // bf16 [384][256]
    short* Wo   = Wq + 384 * 256;                      // bf16 [256][128]
    short* Qb   = Wo + 256 * 128;                      // bf16 [bh][s][dh] (xSCALE*log2e)
    short* Kb   = Qb + (size_t)NB * NH * HW * DH;      // bf16 [bh][s'][dh], sigma-permuted
    short* Vb   = Kb + (size_t)NB * NH * HW * DH;      // bf16 [bh][dh][s]
    short* attT = Vb + (size_t)NB * NH * HW * DH;      // bf16 [b][s][hid]

    prep<<<dim3(HW / 32, NC / 32, NB + 1), 256, 0, stream>>>(
        x, w_qkv, w_out, Xt, Wq, Wo, wsf);
    conv_mfma<NC, true><<<dim3(18, 6, NB), 256, 0, stream>>>(
        Wq, Xt, b_qkv, nullptr, Qb, Kb, Vb, E, nullptr, 0, nullptr);
    flash9<<<dim3(HW / 128, NB * NH), 256, 0, stream>>>(
        Qb, Kb, Vb, attT, E);
    conv_mfma<HID, false><<<dim3(18, 4, NB), 256, 0, stream>>>(
        Wo, attT, b_out, out, nullptr, nullptr, nullptr, E,
        ticket, 18 * 4 * NB, out + (size_t)NB * NC * HW);
}

// Round 4
// 207.755 us; speedup vs baseline: 1.1000x; 1.0016x over previous
//
#include <hip/hip_runtime.h>
#include <hip/hip_bf16.h>

#define HW 2304          // 48*48
#define NB 8             // batch
#define NC 256           // input channels
#define HID 128          // heads*dim_head
#define DH 32            // dim_head
#define NH 4             // heads
#define SCALE 0.17677669529663687f   // 1/sqrt(32)
#define LOG2E 1.4426950408889634f
#define LN2   0.6931471805599453f

using bf16x8 = __attribute__((ext_vector_type(8))) short;
using f32x4  = __attribute__((ext_vector_type(4))) float;

__device__ __forceinline__ short f2bf(float f) {   // RNE float->bf16
    unsigned u = __float_as_uint(f);
    u += 0x7FFF + ((u >> 16) & 1);
    return (short)(u >> 16);
}
__device__ __forceinline__ float bf2f(short s) {
    return __uint_as_float(((unsigned)(unsigned short)s) << 16);
}
__device__ __forceinline__ unsigned pk2bf(float a, float b) {  // pack 2 bf16 (RNE)
    union { __hip_bfloat162 h; unsigned u; } cv;
    cv.h = __float22bfloat162_rn(float2{a, b});
    return cv.u;
}
__device__ __forceinline__ void gld16(const void* g, void* l) {  // 16B global->LDS DMA
    __builtin_amdgcn_global_load_lds(
        (const __attribute__((address_space(1))) unsigned*)g,
        (__attribute__((address_space(3))) unsigned*)l, 16, 0, 0);
}

// ---------------------------------------------------------------------------
// Fused pre-pass. z<8: x [b][256][2304] fp32 -> Xt [b][2304][256] bf16.
// z==8: weight fp32->bf16 conversion + zero the E/ticket words.
// ---------------------------------------------------------------------------
__global__ __launch_bounds__(256)
void prep(const float* __restrict__ x, const float* __restrict__ wq,
          const float* __restrict__ wo, short* __restrict__ Xt,
          short* __restrict__ Wq, short* __restrict__ Wo, float* __restrict__ wsz)
{
    if (blockIdx.z == 8) {
        const int bid = blockIdx.x + 72 * blockIdx.y;
        if (bid == 0 && threadIdx.x == 0) { wsz[0] = 0.f; ((int*)wsz)[1] = 0; }
        const int i = bid * 256 + threadIdx.x;
        if (i < 384 * 256) Wq[i] = f2bf(wq[i]);
        if (i < 256 * 128) Wo[i] = f2bf(wo[i]);
        return;
    }
    __shared__ float T[32][33];
    const int b = blockIdx.z, c0 = blockIdx.y * 32, s0 = blockIdx.x * 32;
    const int ts = threadIdx.x & 31, tc = threadIdx.x >> 5;
    #pragma unroll
    for (int cc = tc; cc < 32; cc += 8)
        T[cc][ts] = x[((size_t)b * NC + c0 + cc) * HW + s0 + ts];
    __syncthreads();
    const int tcc = threadIdx.x & 31, tss = threadIdx.x >> 5;
    #pragma unroll
    for (int ss = tss; ss < 32; ss += 8)
        Xt[((size_t)b * HW + s0 + ss) * NC + c0 + tcc] = f2bf(T[tcc][ss]);
}

// ---------------------------------------------------------------------------
// MFMA 1x1-conv GEMM with gld16-staged, double-buffered LDS tiles (m97-style:
// one barrier per 32-K chunk = DMA drain; MFMA stream never waits on VMEM).
// Tile M64 x N128. LDS per buffer: A 64x32 (4KB, 4 deposit ops) + B 128x32
// (8KB, 8 ops); 12 ops spread 3-per-wave. Deposit lane L holds global column
// block (L&3)^(rL&3) (XOR swizzle); frag read offset (quad^(n16&3))*16.
// Epilogue: Q(xSCALE*LOG2E) [bh][s][dh]; K permuted with sigma(g) =
// ((g&4)<<2)|((g>>3)<<2)|(g&3) within each 32-key group so the swapped
// QK^T lands P directly in PV B-frag layout; V [bh][dh][s]; else fp32 out +
// ticketed energy store.
// ---------------------------------------------------------------------------
template<int KD, bool QKV>
__global__ __launch_bounds__(256, 4)
void conv_mfma(const short* __restrict__ A, const short* __restrict__ Bt,
               const float* __restrict__ bias, float* __restrict__ out0,
               short* __restrict__ Qb, short* __restrict__ Kb,
               short* __restrict__ Vb, float* __restrict__ E,
               int* __restrict__ ticket, int nblocks, float* __restrict__ edst)
{
    const int b  = blockIdx.z;
    const int bm = blockIdx.y * 64;
    const int bn = blockIdx.x * 128;
    const int t  = threadIdx.x;
    const int w  = t >> 6, lane = t & 63;
    const int n16 = lane & 15, quad = lane >> 4;

    __shared__ __align__(16) char csm[24576];   // 2 x (A 4KB | B 8KB)
    __shared__ float red[4];

    // deposit-side global lane addresses
    const int rL = lane >> 2, cswz = (lane & 3) ^ (rL & 3);
    const char* agl = (const char*)(A  + (size_t)(bm + rL) * KD + cswz * 8);
    const char* bgl = (const char*)(Bt + ((size_t)b * HW + bn + rL) * KD + cswz * 8);

    auto issue = [&](int kc, int pbuf) {
        char* base = csm + pbuf * 12288;
        if (w == 0) {
            gld16(agl + (size_t)(0 * 16 * KD + kc) * 2, base + 0 * 1024);
            gld16(agl + (size_t)(1 * 16 * KD + kc) * 2, base + 1 * 1024);
            gld16(bgl + (size_t)(0 * 16 * KD + kc) * 2, base + 4096 + 0 * 1024);
        } else if (w == 1) {
            gld16(agl + (size_t)(2 * 16 * KD + kc) * 2, base + 2 * 1024);
            gld16(agl + (size_t)(3 * 16 * KD + kc) * 2, base + 3 * 1024);
            gld16(bgl + (size_t)(1 * 16 * KD + kc) * 2, base + 4096 + 1 * 1024);
        } else if (w == 2) {
            gld16(bgl + (size_t)(2 * 16 * KD + kc) * 2, base + 4096 + 2 * 1024);
            gld16(bgl + (size_t)(3 * 16 * KD + kc) * 2, base + 4096 + 3 * 1024);
            gld16(bgl + (size_t)(4 * 16 * KD + kc) * 2, base + 4096 + 4 * 1024);
        } else {
            gld16(bgl + (size_t)(5 * 16 * KD + kc) * 2, base + 4096 + 5 * 1024);
            gld16(bgl + (size_t)(6 * 16 * KD + kc) * 2, base + 4096 + 6 * 1024);
            gld16(bgl + (size_t)(7 * 16 * KD + kc) * 2, base + 4096 + 7 * 1024);
        }
    };

    f32x4 acc[4][2] = {};
    const int rsw = (quad ^ (n16 & 3)) * 16;    // frag-read swizzle (bytes)
    constexpr int NI = KD / 32;

    issue(0, 0);
    for (int ki = 0; ki < NI; ++ki) {
        const int p = ki & 1;
        __syncthreads();                        // vmcnt(0) drain: chunk ki landed
        if (ki + 1 < NI) issue((ki + 1) * 32, p ^ 1);

        const char* Ap = csm + p * 12288;
        const char* Bp = Ap + 4096;
        bf16x8 am[4], bq[2];
        #pragma unroll
        for (int tm = 0; tm < 4; ++tm)
            am[tm] = *(const bf16x8*)(Ap + tm * 1024 + n16 * 64 + rsw);
        #pragma unroll
        for (int j = 0; j < 2; ++j)
            bq[j] = *(const bf16x8*)(Bp + (w * 2 + j) * 1024 + n16 * 64 + rsw);
        #pragma unroll
        for (int tm = 0; tm < 4; ++tm)
            #pragma unroll
            for (int j = 0; j < 2; ++j)
                acc[tm][j] = __builtin_amdgcn_mfma_f32_16x16x32_bf16(am[tm], bq[j], acc[tm][j], 0, 0, 0);
    }

    float e = 0.f;
    #pragma unroll
    for (int tm = 0; tm < 4; ++tm) {
        const int o0 = bm + tm * 16 + quad * 4;
        const float4 bb = *(const float4*)(bias + o0);
        #pragma unroll
        for (int j = 0; j < 2; ++j) {
            const int s = bn + (w * 2 + j) * 16 + n16;
            float v[4] = {acc[tm][j][0] + bb.x, acc[tm][j][1] + bb.y,
                          acc[tm][j][2] + bb.z, acc[tm][j][3] + bb.w};
            e -= 0.5f * (v[0]*v[0] + v[1]*v[1] + v[2]*v[2] + v[3]*v[3]);
            if (QKV) {
                if (o0 < HID) {                       // Q: scaled by SCALE*log2e
                    const int h = o0 >> 5, dh0 = o0 & 31;
                    const float qs = SCALE * LOG2E;
                    short4 pk = {f2bf(v[0]*qs), f2bf(v[1]*qs),
                                 f2bf(v[2]*qs), f2bf(v[3]*qs)};
                    *(short4*)(Qb + ((size_t)(b * NH + h) * HW + s) * DH + dh0) = pk;
                } else if (o0 < 2 * HID) {            // K: sigma-permuted rows
                    const int c = o0 - HID, h = c >> 5, dh0 = c & 31;
                    const int g = s & 31;
                    const int sp = (s & ~31) | ((g & 4) << 2) | ((g >> 3) << 2) | (g & 3);
                    short4 pk = {f2bf(v[0]), f2bf(v[1]), f2bf(v[2]), f2bf(v[3])};
                    *(short4*)(Kb + ((size_t)(b * NH + h) * HW + sp) * DH + dh0) = pk;
                } else {                              // V: [bh][dh][s]
                    const int c = o0 - 2 * HID, h = c >> 5, dh0 = c & 31;
                    #pragma unroll
                    for (int r = 0; r < 4; ++r)
                        Vb[((size_t)(b * NH + h) * DH + dh0 + r) * HW + s] = f2bf(v[r]);
                }
            } else {
                #pragma unroll
                for (int r = 0; r < 4; ++r)
                    out0[((size_t)b * NC + o0 + r) * HW + s] = v[r];
            }
        }
    }

    #pragma unroll
    for (int off = 32; off > 0; off >>= 1) e += __shfl_down(e, off);
    if (lane == 0) red[w] = e;
    __syncthreads();
    if (t == 0) {
        atomicAdd(E, red[0] + red[1] + red[2] + red[3]);
        if (!QKV) {
            __threadfence();
            const int prev = atomicAdd(ticket, 1);
            if (prev == nblocks - 1) {
                __threadfence();
                edst[0] = atomicAdd(E, 0.f);
            }
        }
    }
}

// ---------------------------------------------------------------------------
// Flash attention v10 = flash9 (swapped-operand, register softmax) SPLIT-K:
// grid (18 qblocks, 32 bh, 2 key-halves); each block walks 1152 keys in 18
// iterations x 64 keys. m=0 shift => partials combine additively. Epilogue
// writes own-normalized O-partial (bf16, attT layout) + L/ts partials (fp32).
// Per-(block,key) overhead identical to flash9; 2x blocks for latency hiding
// (576 -> 1152 blocks, 2.25 -> 4.5 blocks/CU).
// ---------------------------------------------------------------------------
__global__ __launch_bounds__(256)
void flashsplit(const short* __restrict__ Qb, const short* __restrict__ Kb,
                const short* __restrict__ Vb, short* __restrict__ Oh0,
                short* __restrict__ Oh1, float* __restrict__ lsP,
                float* __restrict__ tsP)
{
    __shared__ __align__(16) char smem[16384];
    // KV buffers: parity p at p*8192, chunk ca at +ca*4096
    // (4KB: K keypos0-15 | keypos16-31 | V dh0-15 | dh16-31, 1KB each)

    const int bh   = blockIdx.y;
    const int kh   = blockIdx.z;               // key half: 0 or 1
    const int w    = threadIdx.x >> 6;
    const int lane = threadIdx.x & 63;
    const int n16  = lane & 15, quad = lane >> 4;
    const int qb   = blockIdx.x * 128 + w * 32;

    bf16x8 aq[2];
    #pragma unroll
    for (int qg = 0; qg < 2; ++qg)
        aq[qg] = *(const bf16x8*)(Qb + ((size_t)bh * HW + qb + qg * 16 + n16) * DH + quad * 8);

    // DMA role: waves 0,1 -> K halves; waves 2,3 -> V halves.
    const int rL = lane >> 2, cL = (lane & 3) ^ (rL & 3);
    const char* gbase; size_t gstep;
    if (w < 2) {
        gbase = (const char*)(Kb + (size_t)bh * HW * DH) + ((w & 1) * 16 + rL) * 64 + cL * 16;
        gstep = 2048;                      // 32 keys * 64 B
    } else {
        gbase = (const char*)(Vb + (size_t)bh * DH * HW)
              + (size_t)((w & 1) * 16 + rL) * (HW * 2) + cL * 16;
        gstep = 64;                        // 32 keys * 2 B per dh-row
    }
    gbase += (size_t)kh * 36 * gstep;      // jump to this block's key half (1152 keys)

    // preload iteration 0 (chunks 0,1) -> parity 0
    gld16(gbase,         smem + 0    + w * 1024);
    gld16(gbase + gstep, smem + 4096 + w * 1024);

    f32x4 acc[2][2] = {};                     // [qg][dh-half]: O^T[q=n16][dh]
    float ls[2] = {}, ts[2] = {};             // lane-local partials, query (qg,n16)
    const int swz = (quad ^ (n16 & 3)) * 8;   // frag-read XOR swizzle (shorts)

    for (int it = 0; it < 18; ++it) {
        const int p = it & 1;
        __syncthreads();                   // pair `it` landed; pair it-1 fully read
        if (it + 1 < 18) {
            const size_t g0 = (size_t)(2 * it + 2) * gstep;
            gld16(gbase + g0,         smem + (p ^ 1) * 8192 + 0    + w * 1024);
            gld16(gbase + g0 + gstep, smem + (p ^ 1) * 8192 + 4096 + w * 1024);
        }

        #pragma unroll
        for (int ca = 0; ca < 2; ++ca) {
            const short* kb = (const short*)(smem + p * 8192 + ca * 4096);

            const bf16x8 bk0 = *(const bf16x8*)(kb + n16 * 32 + swz);          // keypos 0-15
            const bf16x8 bk1 = *(const bf16x8*)(kb + 512  + n16 * 32 + swz);   // keypos 16-31
            const bf16x8 bv0 = *(const bf16x8*)(kb + 1024 + n16 * 32 + swz);   // dh 0-15
            const bf16x8 bv1 = *(const bf16x8*)(kb + 1536 + n16 * 32 + swz);   // dh 16-31

            #pragma unroll
            for (int qg = 0; qg < 2; ++qg) {
                f32x4 z = {};
                // swapped: C row = key position, col = query n16
                const f32x4 s0 = __builtin_amdgcn_mfma_f32_16x16x32_bf16(bk0, aq[qg], z, 0, 0, 0);
                const f32x4 s1 = __builtin_amdgcn_mfma_f32_16x16x32_bf16(bk1, aq[qg], z, 0, 0, 0);
                float e0[4], e1[4];
                #pragma unroll
                for (int r = 0; r < 4; ++r) {
                    e0[r] = __builtin_amdgcn_exp2f(s0[r]);   // key quad*8+r
                    e1[r] = __builtin_amdgcn_exp2f(s1[r]);   // key quad*8+4+r
                }
                ls[qg] += (e0[0] + e0[1]) + (e0[2] + e0[3])
                        + (e1[0] + e1[1]) + (e1[2] + e1[3]);
                ts[qg] += (e0[0]*s0[0] + e0[1]*s0[1]) + (e0[2]*s0[2] + e0[3]*s0[3])
                        + (e1[0]*s1[0] + e1[1]*s1[1]) + (e1[2]*s1[2] + e1[3]*s1[3]);
                union { bf16x8 v; unsigned u[4]; } pa;
                pa.u[0] = pk2bf(e0[0], e0[1]);
                pa.u[1] = pk2bf(e0[2], e0[3]);
                pa.u[2] = pk2bf(e1[0], e1[1]);
                pa.u[3] = pk2bf(e1[2], e1[3]);
                // swapped PV: C row = dh part, col = query n16
                acc[qg][0] = __builtin_amdgcn_mfma_f32_16x16x32_bf16(bv0, pa.v, acc[qg][0], 0, 0, 0);
                acc[qg][1] = __builtin_amdgcn_mfma_f32_16x16x32_bf16(bv1, pa.v, acc[qg][1], 0, 0, 0);
            }
        }
    }

    // reduce ls/ts across the 4 quad lanes (key blocks) of each query
    #pragma unroll
    for (int qg = 0; qg < 2; ++qg) {
        ls[qg] += __shfl_xor(ls[qg], 16);
        ls[qg] += __shfl_xor(ls[qg], 32);
        ts[qg] += __shfl_xor(ts[qg], 16);
        ts[qg] += __shfl_xor(ts[qg], 32);
    }

    const int bb = bh >> 2, h = bh & 3;
    short* dst = kh ? Oh1 : Oh0;
    #pragma unroll
    for (int qg = 0; qg < 2; ++qg) {
        const int q = qb + qg * 16 + n16;
        const float L = ls[qg];
        const float invl = 1.f / L;
        short* ap = dst + ((size_t)bb * HW + q) * HID + h * 32;
        short4 pk0 = {f2bf(acc[qg][0][0] * invl), f2bf(acc[qg][0][1] * invl),
                      f2bf(acc[qg][0][2] * invl), f2bf(acc[qg][0][3] * invl)};
        short4 pk1 = {f2bf(acc[qg][1][0] * invl), f2bf(acc[qg][1][1] * invl),
                      f2bf(acc[qg][1][2] * invl), f2bf(acc[qg][1][3] * invl)};
        *(short4*)(ap + quad * 4)      = pk0;   // dh quad*4 .. +3
        *(short4*)(ap + 16 + quad * 4) = pk1;   // dh 16+quad*4 .. +3
        if (quad == 0) {
            const size_t li = (size_t)(kh * 32 + bh) * HW + q;
            lsP[li] = L;
            tsP[li] = ts[qg];
        }
    }
}

// ---------------------------------------------------------------------------
// Combine: O = (L0*O0 + L1*O1)/(L0+L1) in-place into attT (=Oh0), plus the
// softmax-Lagrangian energy e_q = LN2*(ts0+ts1)/L - log(L). Memory-bound.
// Grid (36, 32bh), 256 threads: thread t -> q = qb + t/4, dh octet (t&3)*8.
// ---------------------------------------------------------------------------
__global__ __launch_bounds__(256)
void combine(short* __restrict__ attT, const short* __restrict__ Oh1,
             const float* __restrict__ lsP, const float* __restrict__ tsP,
             float* __restrict__ E)
{
    __shared__ float red[4];
    const int bh = blockIdx.y, b = bh >> 2, h = bh & 3;
    const int t = threadIdx.x;
    const int q = blockIdx.x * 64 + (t >> 2);
    const int dg = (t & 3) * 8;
    const size_t l0 = (size_t)bh * HW + q;            // kh=0 partial
    const size_t l1 = (size_t)(32 + bh) * HW + q;     // kh=1 partial
    const float L0 = lsP[l0], L1 = lsP[l1];
    const float L = L0 + L1;
    const float w0 = L0 / L, w1 = L1 / L;

    short* ap = attT + ((size_t)b * HW + q) * HID + h * 32 + dg;
    const short* bp = Oh1 + ((size_t)b * HW + q) * HID + h * 32 + dg;
    const bf16x8 o0 = *(const bf16x8*)ap;
    const bf16x8 o1 = *(const bf16x8*)bp;
    union { bf16x8 v; unsigned u[4]; } pk;
    #pragma unroll
    for (int i = 0; i < 4; ++i)
        pk.u[i] = pk2bf(w0 * bf2f(o0[2*i])     + w1 * bf2f(o1[2*i]),
                        w0 * bf2f(o0[2*i + 1]) + w1 * bf2f(o1[2*i + 1]));
    *(bf16x8*)ap = pk.v;

    float e = 0.f;
    if ((t & 3) == 0)
        e = (LN2 * (tsP[l0] + tsP[l1])) / L - __logf(L);
    #pragma unroll
    for (int off = 32; off > 0; off >>= 1) e += __shfl_down(e, off);
    if ((t & 63) == 0) red[t >> 6] = e;
    __syncthreads();
    if (t == 0) atomicAdd(E, red[0] + red[1] + red[2] + red[3]);
}

// ---------------------------------------------------------------------------
extern "C" void kernel_launch(void* const* d_in, const int* in_sizes, int n_in,
                              void* d_out, int out_size, void* d_ws, size_t ws_size,
                              hipStream_t stream) {
    const float* x     = (const float*)d_in[0];
    const float* w_qkv = (const float*)d_in[1];
    const float* b_qkv = (const float*)d_in[2];
    const float* w_out = (const float*)d_in[3];
    const float* b_out = (const float*)d_in[4];
    float* out = (float*)d_out;

    float* wsf    = (float*)d_ws;
    float* E      = wsf;                               // [0] energy accumulator
    int*   ticket = (int*)d_ws + 1;                    // [1] conv2 ticket
    short* Xt   = (short*)(wsf + 16);                  // bf16 [b][s][c]
    short* Wq   = Xt + (size_t)NB * HW * NC;           // bf16 [384][256]
    short* Wo   = Wq + 384 * 256;                      // bf16 [256][128]
    short* Qb   = Wo + 256 * 128;                      // bf16 [bh][s][dh] (xSCALE*log2e)
    short* Kb   = Qb + (size_t)NB * NH * HW * DH;      // bf16 [bh][s'][dh], sigma-permuted
    short* Vb   = Kb + (size_t)NB * NH * HW * DH;      // bf16 [bh][dh][s]
    short* attT = Vb + (size_t)NB * NH * HW * DH;      // bf16 [b][s][hid]; doubles as Oh0
    short* attT2= attT + (size_t)NB * HW * HID;        // bf16 [b][s][hid] (kh=1 partial)
    float* lsP  = (float*)(attT2 + (size_t)NB * HW * HID);  // f32 [2][32][HW]
    float* tsP  = lsP + 2 * 32 * HW;                        // f32 [2][32][HW]

    prep<<<dim3(HW / 32, NC / 32, NB + 1), 256, 0, stream>>>(
        x, w_qkv, w_out, Xt, Wq, Wo, wsf);
    conv_mfma<NC, true><<<dim3(18, 6, NB), 256, 0, stream>>>(
        Wq, Xt, b_qkv, nullptr, Qb, Kb, Vb, E, nullptr, 0, nullptr);
    flashsplit<<<dim3(18, NB * NH, 2), 256, 0, stream>>>(
        Qb, Kb, Vb, attT, attT2, lsP, tsP);
    combine<<<dim3(HW / 64, NB * NH), 256, 0, stream>>>(
        attT, attT2, lsP, tsP, E);
    conv_mfma<HID, false><<<dim3(18, 4, NB), 256, 0, stream>>>(
        Wo, attT, b_out, out, nullptr, nullptr, nullptr, E,
        ticket, 18 * 4 * NB, out + (size_t)NB * NC * HW);
}

// Round 5
// 196.326 us; speedup vs baseline: 1.1641x; 1.0582x over previous
//
#include <hip/hip_runtime.h>
#include <hip/hip_bf16.h>

#define HW 2304          // 48*48
#define NB 8             // batch
#define NC 256           // input channels
#define HID 128          // heads*dim_head
#define DH 32            // dim_head
#define NH 4             // heads
#define SCALE 0.17677669529663687f   // 1/sqrt(32)
#define LOG2E 1.4426950408889634f
#define LN2   0.6931471805599453f

#define NSPLIT 4         // flash split-K factor
#define OSZ ((size_t)NB * HW * HID)   // one O-partial

using bf16x8 = __attribute__((ext_vector_type(8))) short;
using f32x4  = __attribute__((ext_vector_type(4))) float;

__device__ __forceinline__ short f2bf(float f) {   // RNE float->bf16
    unsigned u = __float_as_uint(f);
    u += 0x7FFF + ((u >> 16) & 1);
    return (short)(u >> 16);
}
__device__ __forceinline__ float bf2f(short s) {
    return __uint_as_float(((unsigned)(unsigned short)s) << 16);
}
__device__ __forceinline__ unsigned pk2bf(float a, float b) {  // pack 2 bf16 (RNE)
    union { __hip_bfloat162 h; unsigned u; } cv;
    cv.h = __float22bfloat162_rn(float2{a, b});
    return cv.u;
}
__device__ __forceinline__ void gld16(const void* g, void* l) {  // 16B global->LDS DMA
    __builtin_amdgcn_global_load_lds(
        (const __attribute__((address_space(1))) unsigned*)g,
        (__attribute__((address_space(3))) unsigned*)l, 16, 0, 0);
}

// ---------------------------------------------------------------------------
// Fused pre-pass. z<8: x [b][256][2304] fp32 -> Xt [b][2304][256] bf16.
// z==8: weight fp32->bf16 conversion + zero the E/ticket words.
// ---------------------------------------------------------------------------
__global__ __launch_bounds__(256)
void prep(const float* __restrict__ x, const float* __restrict__ wq,
          const float* __restrict__ wo, short* __restrict__ Xt,
          short* __restrict__ Wq, short* __restrict__ Wo, float* __restrict__ wsz)
{
    if (blockIdx.z == 8) {
        const int bid = blockIdx.x + 72 * blockIdx.y;
        if (bid == 0 && threadIdx.x == 0) { wsz[0] = 0.f; ((int*)wsz)[1] = 0; }
        const int i = bid * 256 + threadIdx.x;
        if (i < 384 * 256) Wq[i] = f2bf(wq[i]);
        if (i < 256 * 128) Wo[i] = f2bf(wo[i]);
        return;
    }
    __shared__ float T[32][33];
    const int b = blockIdx.z, c0 = blockIdx.y * 32, s0 = blockIdx.x * 32;
    const int ts = threadIdx.x & 31, tc = threadIdx.x >> 5;
    #pragma unroll
    for (int cc = tc; cc < 32; cc += 8)
        T[cc][ts] = x[((size_t)b * NC + c0 + cc) * HW + s0 + ts];
    __syncthreads();
    const int tcc = threadIdx.x & 31, tss = threadIdx.x >> 5;
    #pragma unroll
    for (int ss = tss; ss < 32; ss += 8)
        Xt[((size_t)b * HW + s0 + ss) * NC + c0 + tcc] = f2bf(T[tcc][ss]);
}

// ---------------------------------------------------------------------------
// QKV MFMA 1x1-conv GEMM (unchanged): gld16-staged, double-buffered LDS,
// one barrier per 32-K chunk. Tile M64 x N128. Epilogue: Q(xSCALE*LOG2E)
// [bh][s][dh]; K sigma-permuted (sigma(g)=((g&4)<<2)|((g>>3)<<2)|(g&3)) so
// flash's swapped QK^T lands P directly in PV B-frag layout; V [bh][dh][s].
// ---------------------------------------------------------------------------
__global__ __launch_bounds__(256, 4)
void conv_qkv(const short* __restrict__ A, const short* __restrict__ Bt,
              const float* __restrict__ bias,
              short* __restrict__ Qb, short* __restrict__ Kb,
              short* __restrict__ Vb, float* __restrict__ E)
{
    constexpr int KD = NC;
    const int b  = blockIdx.z;
    const int bm = blockIdx.y * 64;
    const int bn = blockIdx.x * 128;
    const int t  = threadIdx.x;
    const int w  = t >> 6, lane = t & 63;
    const int n16 = lane & 15, quad = lane >> 4;

    __shared__ __align__(16) char csm[24576];   // 2 x (A 4KB | B 8KB)
    __shared__ float red[4];

    const int rL = lane >> 2, cswz = (lane & 3) ^ (rL & 3);
    const char* agl = (const char*)(A  + (size_t)(bm + rL) * KD + cswz * 8);
    const char* bgl = (const char*)(Bt + ((size_t)b * HW + bn + rL) * KD + cswz * 8);

    auto issue = [&](int kc, int pbuf) {
        char* base = csm + pbuf * 12288;
        if (w == 0) {
            gld16(agl + (size_t)(0 * 16 * KD + kc) * 2, base + 0 * 1024);
            gld16(agl + (size_t)(1 * 16 * KD + kc) * 2, base + 1 * 1024);
            gld16(bgl + (size_t)(0 * 16 * KD + kc) * 2, base + 4096 + 0 * 1024);
        } else if (w == 1) {
            gld16(agl + (size_t)(2 * 16 * KD + kc) * 2, base + 2 * 1024);
            gld16(agl + (size_t)(3 * 16 * KD + kc) * 2, base + 3 * 1024);
            gld16(bgl + (size_t)(1 * 16 * KD + kc) * 2, base + 4096 + 1 * 1024);
        } else if (w == 2) {
            gld16(bgl + (size_t)(2 * 16 * KD + kc) * 2, base + 4096 + 2 * 1024);
            gld16(bgl + (size_t)(3 * 16 * KD + kc) * 2, base + 4096 + 3 * 1024);
            gld16(bgl + (size_t)(4 * 16 * KD + kc) * 2, base + 4096 + 4 * 1024);
        } else {
            gld16(bgl + (size_t)(5 * 16 * KD + kc) * 2, base + 4096 + 5 * 1024);
            gld16(bgl + (size_t)(6 * 16 * KD + kc) * 2, base + 4096 + 6 * 1024);
            gld16(bgl + (size_t)(7 * 16 * KD + kc) * 2, base + 4096 + 7 * 1024);
        }
    };

    f32x4 acc[4][2] = {};
    const int rsw = (quad ^ (n16 & 3)) * 16;    // frag-read swizzle (bytes)
    constexpr int NI = KD / 32;

    issue(0, 0);
    for (int ki = 0; ki < NI; ++ki) {
        const int p = ki & 1;
        __syncthreads();                        // vmcnt(0) drain: chunk ki landed
        if (ki + 1 < NI) issue((ki + 1) * 32, p ^ 1);

        const char* Ap = csm + p * 12288;
        const char* Bp = Ap + 4096;
        bf16x8 am[4], bq[2];
        #pragma unroll
        for (int tm = 0; tm < 4; ++tm)
            am[tm] = *(const bf16x8*)(Ap + tm * 1024 + n16 * 64 + rsw);
        #pragma unroll
        for (int j = 0; j < 2; ++j)
            bq[j] = *(const bf16x8*)(Bp + (w * 2 + j) * 1024 + n16 * 64 + rsw);
        #pragma unroll
        for (int tm = 0; tm < 4; ++tm)
            #pragma unroll
            for (int j = 0; j < 2; ++j)
                acc[tm][j] = __builtin_amdgcn_mfma_f32_16x16x32_bf16(am[tm], bq[j], acc[tm][j], 0, 0, 0);
    }

    float e = 0.f;
    #pragma unroll
    for (int tm = 0; tm < 4; ++tm) {
        const int o0 = bm + tm * 16 + quad * 4;
        const float4 bb = *(const float4*)(bias + o0);
        #pragma unroll
        for (int j = 0; j < 2; ++j) {
            const int s = bn + (w * 2 + j) * 16 + n16;
            float v[4] = {acc[tm][j][0] + bb.x, acc[tm][j][1] + bb.y,
                          acc[tm][j][2] + bb.z, acc[tm][j][3] + bb.w};
            e -= 0.5f * (v[0]*v[0] + v[1]*v[1] + v[2]*v[2] + v[3]*v[3]);
            if (o0 < HID) {                       // Q: scaled by SCALE*log2e
                const int h = o0 >> 5, dh0 = o0 & 31;
                const float qs = SCALE * LOG2E;
                short4 pk = {f2bf(v[0]*qs), f2bf(v[1]*qs),
                             f2bf(v[2]*qs), f2bf(v[3]*qs)};
                *(short4*)(Qb + ((size_t)(b * NH + h) * HW + s) * DH + dh0) = pk;
            } else if (o0 < 2 * HID) {            // K: sigma-permuted rows
                const int c = o0 - HID, h = c >> 5, dh0 = c & 31;
                const int g = s & 31;
                const int sp = (s & ~31) | ((g & 4) << 2) | ((g >> 3) << 2) | (g & 3);
                short4 pk = {f2bf(v[0]), f2bf(v[1]), f2bf(v[2]), f2bf(v[3])};
                *(short4*)(Kb + ((size_t)(b * NH + h) * HW + sp) * DH + dh0) = pk;
            } else {                              // V: [bh][dh][s]
                const int c = o0 - 2 * HID, h = c >> 5, dh0 = c & 31;
                #pragma unroll
                for (int r = 0; r < 4; ++r)
                    Vb[((size_t)(b * NH + h) * DH + dh0 + r) * HW + s] = f2bf(v[r]);
            }
        }
    }

    #pragma unroll
    for (int off = 32; off > 0; off >>= 1) e += __shfl_down(e, off);
    if (lane == 0) red[w] = e;
    __syncthreads();
    if (t == 0) atomicAdd(E, red[0] + red[1] + red[2] + red[3]);
}

// ---------------------------------------------------------------------------
// Flash attention v11 = flashsplit with NSPLIT=4 key quarters: grid (18 q,
// 32 bh, 4 kh); each block walks 576 keys in 9 iterations x 64 keys.
// Swapped-operand MFMAs + register softmax (m=0 shift => additive combine).
// Epilogue: own-normalized O-partial (bf16) into Oh[kh] + L/ts (fp32).
// 2304 blocks -> ~9 blocks/CU for latency hiding.
// ---------------------------------------------------------------------------
__global__ __launch_bounds__(256)
void flashsplit(const short* __restrict__ Qb, const short* __restrict__ Kb,
                const short* __restrict__ Vb, short* __restrict__ Oh,
                float* __restrict__ lsP, float* __restrict__ tsP)
{
    __shared__ __align__(16) char smem[16384];
    // KV buffers: parity p at p*8192, chunk ca at +ca*4096
    // (4KB: K keypos0-15 | keypos16-31 | V dh0-15 | dh16-31, 1KB each)

    constexpr int ITERS = HW / (NSPLIT * 64);   // 9
    const int bh   = blockIdx.y;
    const int kh   = blockIdx.z;                // key quarter: 0..3
    const int w    = threadIdx.x >> 6;
    const int lane = threadIdx.x & 63;
    const int n16  = lane & 15, quad = lane >> 4;
    const int qb   = blockIdx.x * 128 + w * 32;

    bf16x8 aq[2];
    #pragma unroll
    for (int qg = 0; qg < 2; ++qg)
        aq[qg] = *(const bf16x8*)(Qb + ((size_t)bh * HW + qb + qg * 16 + n16) * DH + quad * 8);

    // DMA role: waves 0,1 -> K halves; waves 2,3 -> V halves.
    const int rL = lane >> 2, cL = (lane & 3) ^ (rL & 3);
    const char* gbase; size_t gstep;
    if (w < 2) {
        gbase = (const char*)(Kb + (size_t)bh * HW * DH) + ((w & 1) * 16 + rL) * 64 + cL * 16;
        gstep = 2048;                      // 32 keys * 64 B
    } else {
        gbase = (const char*)(Vb + (size_t)bh * DH * HW)
              + (size_t)((w & 1) * 16 + rL) * (HW * 2) + cL * 16;
        gstep = 64;                        // 32 keys * 2 B per dh-row
    }
    gbase += (size_t)kh * (2 * ITERS) * gstep;  // this block's key quarter (576 keys)

    // preload iteration 0 (chunks 0,1) -> parity 0
    gld16(gbase,         smem + 0    + w * 1024);
    gld16(gbase + gstep, smem + 4096 + w * 1024);

    f32x4 acc[2][2] = {};                     // [qg][dh-half]: O^T[q=n16][dh]
    float ls[2] = {}, ts[2] = {};             // lane-local partials, query (qg,n16)
    const int swz = (quad ^ (n16 & 3)) * 8;   // frag-read XOR swizzle (shorts)

    for (int it = 0; it < ITERS; ++it) {
        const int p = it & 1;
        __syncthreads();                   // pair `it` landed; pair it-1 fully read
        if (it + 1 < ITERS) {
            const size_t g0 = (size_t)(2 * it + 2) * gstep;
            gld16(gbase + g0,         smem + (p ^ 1) * 8192 + 0    + w * 1024);
            gld16(gbase + g0 + gstep, smem + (p ^ 1) * 8192 + 4096 + w * 1024);
        }

        #pragma unroll
        for (int ca = 0; ca < 2; ++ca) {
            const short* kb = (const short*)(smem + p * 8192 + ca * 4096);

            const bf16x8 bk0 = *(const bf16x8*)(kb + n16 * 32 + swz);          // keypos 0-15
            const bf16x8 bk1 = *(const bf16x8*)(kb + 512  + n16 * 32 + swz);   // keypos 16-31
            const bf16x8 bv0 = *(const bf16x8*)(kb + 1024 + n16 * 32 + swz);   // dh 0-15
            const bf16x8 bv1 = *(const bf16x8*)(kb + 1536 + n16 * 32 + swz);   // dh 16-31

            #pragma unroll
            for (int qg = 0; qg < 2; ++qg) {
                f32x4 z = {};
                // swapped: C row = key position, col = query n16
                const f32x4 s0 = __builtin_amdgcn_mfma_f32_16x16x32_bf16(bk0, aq[qg], z, 0, 0, 0);
                const f32x4 s1 = __builtin_amdgcn_mfma_f32_16x16x32_bf16(bk1, aq[qg], z, 0, 0, 0);
                float e0[4], e1[4];
                #pragma unroll
                for (int r = 0; r < 4; ++r) {
                    e0[r] = __builtin_amdgcn_exp2f(s0[r]);   // key quad*8+r
                    e1[r] = __builtin_amdgcn_exp2f(s1[r]);   // key quad*8+4+r
                }
                ls[qg] += (e0[0] + e0[1]) + (e0[2] + e0[3])
                        + (e1[0] + e1[1]) + (e1[2] + e1[3]);
                ts[qg] += (e0[0]*s0[0] + e0[1]*s0[1]) + (e0[2]*s0[2] + e0[3]*s0[3])
                        + (e1[0]*s1[0] + e1[1]*s1[1]) + (e1[2]*s1[2] + e1[3]*s1[3]);
                union { bf16x8 v; unsigned u[4]; } pa;
                pa.u[0] = pk2bf(e0[0], e0[1]);
                pa.u[1] = pk2bf(e0[2], e0[3]);
                pa.u[2] = pk2bf(e1[0], e1[1]);
                pa.u[3] = pk2bf(e1[2], e1[3]);
                // swapped PV: C row = dh part, col = query n16
                acc[qg][0] = __builtin_amdgcn_mfma_f32_16x16x32_bf16(bv0, pa.v, acc[qg][0], 0, 0, 0);
                acc[qg][1] = __builtin_amdgcn_mfma_f32_16x16x32_bf16(bv1, pa.v, acc[qg][1], 0, 0, 0);
            }
        }
    }

    // reduce ls/ts across the 4 quad lanes (key blocks) of each query
    #pragma unroll
    for (int qg = 0; qg < 2; ++qg) {
        ls[qg] += __shfl_xor(ls[qg], 16);
        ls[qg] += __shfl_xor(ls[qg], 32);
        ts[qg] += __shfl_xor(ts[qg], 16);
        ts[qg] += __shfl_xor(ts[qg], 32);
    }

    const int bb = bh >> 2, h = bh & 3;
    short* dst = Oh + (size_t)kh * OSZ;
    #pragma unroll
    for (int qg = 0; qg < 2; ++qg) {
        const int q = qb + qg * 16 + n16;
        const float L = ls[qg];
        const float invl = 1.f / L;
        short* ap = dst + ((size_t)bb * HW + q) * HID + h * 32;
        short4 pk0 = {f2bf(acc[qg][0][0] * invl), f2bf(acc[qg][0][1] * invl),
                      f2bf(acc[qg][0][2] * invl), f2bf(acc[qg][0][3] * invl)};
        short4 pk1 = {f2bf(acc[qg][1][0] * invl), f2bf(acc[qg][1][1] * invl),
                      f2bf(acc[qg][1][2] * invl), f2bf(acc[qg][1][3] * invl)};
        *(short4*)(ap + quad * 4)      = pk0;   // dh quad*4 .. +3
        *(short4*)(ap + 16 + quad * 4) = pk1;   // dh 16+quad*4 .. +3
        if (quad == 0) {
            const size_t li = (size_t)(kh * 32 + bh) * HW + q;
            lsP[li] = L;
            tsP[li] = ts[qg];
        }
    }
}

// ---------------------------------------------------------------------------
// Output conv with FUSED split-K combine: B-tile = sum_kh w_kh*Oh[kh], built
// in registers (T14 issue-early/write-late) and ds_write'n into the same LDS
// layout the gld16 path used. K-chunk ki covers hid [32ki,32ki+32) == head ki,
// so combine weights are per-(pixel,chunk) scalars w_kh = L_kh/sum(L).
// bm==0 blocks also fold in the softmax-Lagrangian energy from lsP/tsP.
// A (Wo) staging via gld16 unchanged. Epilogue: fp32 out + e_out + ticket.
// ---------------------------------------------------------------------------
__global__ __launch_bounds__(256, 2)
void conv_out(const short* __restrict__ A, const short* __restrict__ Oh,
              const float* __restrict__ lsP, const float* __restrict__ tsP,
              const float* __restrict__ bias, float* __restrict__ out0,
              float* __restrict__ E, int* __restrict__ ticket, int nblocks,
              float* __restrict__ edst)
{
    constexpr int KD = HID;                     // 128
    constexpr int NI = KD / 32;                 // 4 chunks == 4 heads
    const int b  = blockIdx.z;
    const int bm = blockIdx.y * 64;
    const int bn = blockIdx.x * 128;
    const int t  = threadIdx.x;
    const int w  = t >> 6, lane = t & 63;
    const int n16 = lane & 15, quad = lane >> 4;

    __shared__ __align__(16) char csm[24576];   // 2 x (A 4KB | B 8KB)
    __shared__ float red[4];

    const int rL = lane >> 2, cswz = (lane & 3) ^ (rL & 3);
    const char* agl = (const char*)(A + (size_t)(bm + rL) * KD + cswz * 8);

    auto issueA = [&](int kc, int pbuf) {       // 4 x 1KB, waves 0-1
        char* base = csm + pbuf * 12288;
        if (w == 0) {
            gld16(agl + (size_t)(0 * 16 * KD + kc) * 2, base + 0 * 1024);
            gld16(agl + (size_t)(1 * 16 * KD + kc) * 2, base + 1 * 1024);
        } else if (w == 1) {
            gld16(agl + (size_t)(2 * 16 * KD + kc) * 2, base + 2 * 1024);
            gld16(agl + (size_t)(3 * 16 * KD + kc) * 2, base + 3 * 1024);
        }
    };

    // fused-combine B loader: 2 deposits/wave (16-pixel blocks w*2, w*2+1)
    auto loadB = [&](int ki, bf16x8 pk[2]) {
        const int kc = ki * 32;
        const int bh = b * NH + ki;             // chunk == head
        #pragma unroll
        for (int d = 0; d < 2; ++d) {
            const int blk = w * 2 + d;
            const int q = bn + blk * 16 + rL;
            float Ls[NSPLIT], sum = 0.f;
            #pragma unroll
            for (int kh = 0; kh < NSPLIT; ++kh) {
                Ls[kh] = lsP[(size_t)(kh * 32 + bh) * HW + q];
                sum += Ls[kh];
            }
            const float inv = 1.f / sum;
            float vv[8] = {};
            #pragma unroll
            for (int kh = 0; kh < NSPLIT; ++kh) {
                const float wk = Ls[kh] * inv;
                const bf16x8 o = *(const bf16x8*)(Oh + (size_t)kh * OSZ
                                    + ((size_t)b * HW + q) * HID + kc + cswz * 8);
                #pragma unroll
                for (int j = 0; j < 8; ++j) vv[j] += wk * bf2f(o[j]);
            }
            union { bf16x8 v; unsigned u[4]; } c;
            #pragma unroll
            for (int i = 0; i < 4; ++i) c.u[i] = pk2bf(vv[2*i], vv[2*i+1]);
            pk[d] = c.v;
        }
    };
    auto writeB = [&](const bf16x8 pk[2], int pbuf) {
        char* base = csm + pbuf * 12288 + 4096;
        #pragma unroll
        for (int d = 0; d < 2; ++d) {
            const int blk = w * 2 + d;
            *(bf16x8*)(base + blk * 1024 + rL * 64 + (lane & 3) * 16) = pk[d];
        }
    };

    f32x4 acc[4][2] = {};
    const int rsw = (quad ^ (n16 & 3)) * 16;    // frag-read swizzle (bytes)

    bf16x8 bpk[2];
    loadB(0, bpk);
    issueA(0, 0);
    writeB(bpk, 0);
    for (int ki = 0; ki < NI; ++ki) {
        const int p = ki & 1;
        __syncthreads();                        // chunk ki landed (A DMA + B writes)
        if (ki + 1 < NI) { loadB(ki + 1, bpk); issueA((ki + 1) * 32, p ^ 1); }

        const char* Ap = csm + p * 12288;
        const char* Bp = Ap + 4096;
        bf16x8 am[4], bq[2];
        #pragma unroll
        for (int tm = 0; tm < 4; ++tm)
            am[tm] = *(const bf16x8*)(Ap + tm * 1024 + n16 * 64 + rsw);
        #pragma unroll
        for (int j = 0; j < 2; ++j)
            bq[j] = *(const bf16x8*)(Bp + (w * 2 + j) * 1024 + n16 * 64 + rsw);
        #pragma unroll
        for (int tm = 0; tm < 4; ++tm)
            #pragma unroll
            for (int j = 0; j < 2; ++j)
                acc[tm][j] = __builtin_amdgcn_mfma_f32_16x16x32_bf16(am[tm], bq[j], acc[tm][j], 0, 0, 0);

        if (ki + 1 < NI) writeB(bpk, p ^ 1);    // after this chunk's frag reads
    }

    float e = 0.f;
    #pragma unroll
    for (int tm = 0; tm < 4; ++tm) {
        const int o0 = bm + tm * 16 + quad * 4;
        const float4 bb = *(const float4*)(bias + o0);
        #pragma unroll
        for (int j = 0; j < 2; ++j) {
            const int s = bn + (w * 2 + j) * 16 + n16;
            float v[4] = {acc[tm][j][0] + bb.x, acc[tm][j][1] + bb.y,
                          acc[tm][j][2] + bb.z, acc[tm][j][3] + bb.w};
            e -= 0.5f * (v[0]*v[0] + v[1]*v[1] + v[2]*v[2] + v[3]*v[3]);
            #pragma unroll
            for (int r = 0; r < 4; ++r)
                out0[((size_t)b * NC + o0 + r) * HW + s] = v[r];
        }
    }

    if (blockIdx.y == 0) {                      // attention energy, once per (b,q,h)
        const int q = bn + (t & 127);
        #pragma unroll
        for (int jj = 0; jj < 2; ++jj) {
            const int h = (t >> 7) * 2 + jj;
            const int bh = b * NH + h;
            float L = 0.f, T = 0.f;
            #pragma unroll
            for (int kh = 0; kh < NSPLIT; ++kh) {
                L += lsP[(size_t)(kh * 32 + bh) * HW + q];
                T += tsP[(size_t)(kh * 32 + bh) * HW + q];
            }
            e += (LN2 * T) / L - __logf(L);
        }
    }

    #pragma unroll
    for (int off = 32; off > 0; off >>= 1) e += __shfl_down(e, off);
    if (lane == 0) red[w] = e;
    __syncthreads();
    if (t == 0) {
        atomicAdd(E, red[0] + red[1] + red[2] + red[3]);
        __threadfence();
        const int prev = atomicAdd(ticket, 1);
        if (prev == nblocks - 1) {
            __threadfence();
            edst[0] = atomicAdd(E, 0.f);
        }
    }
}

// ---------------------------------------------------------------------------
extern "C" void kernel_launch(void* const* d_in, const int* in_sizes, int n_in,
                              void* d_out, int out_size, void* d_ws, size_t ws_size,
                              hipStream_t stream) {
    const float* x     = (const float*)d_in[0];
    const float* w_qkv = (const float*)d_in[1];
    const float* b_qkv = (const float*)d_in[2];
    const float* w_out = (const float*)d_in[3];
    const float* b_out = (const float*)d_in[4];
    float* out = (float*)d_out;

    float* wsf    = (float*)d_ws;
    float* E      = wsf;                               // [0] energy accumulator
    int*   ticket = (int*)d_ws + 1;                    // [1] conv_out ticket
    short* Xt   = (short*)(wsf + 16);                  // bf16 [b][s][c]
    short* Wq   = Xt + (size_t)NB * HW * NC;           // bf16 [384][256]
    short* Wo   = Wq + 384 * 256;                      // bf16 [256][128]
    short* Qb   = Wo + 256 * 128;                      // bf16 [bh][s][dh] (xSCALE*log2e)
    short* Kb   = Qb + (size_t)NB * NH * HW * DH;      // bf16 [bh][s'][dh], sigma-permuted
    short* Vb   = Kb + (size_t)NB * NH * HW * DH;      // bf16 [bh][dh][s]
    short* Oh   = Vb + (size_t)NB * NH * HW * DH;      // bf16 [NSPLIT][b][s][hid]
    float* lsP  = (float*)(Oh + NSPLIT * OSZ);         // f32 [NSPLIT][32][HW]
    float* tsP  = lsP + NSPLIT * 32 * HW;              // f32 [NSPLIT][32][HW]

    prep<<<dim3(HW / 32, NC / 32, NB + 1), 256, 0, stream>>>(
        x, w_qkv, w_out, Xt, Wq, Wo, wsf);
    conv_qkv<<<dim3(18, 6, NB), 256, 0, stream>>>(
        Wq, Xt, b_qkv, Qb, Kb, Vb, E);
    flashsplit<<<dim3(HW / 128, NB * NH, NSPLIT), 256, 0, stream>>>(
        Qb, Kb, Vb, Oh, lsP, tsP);
    conv_out<<<dim3(18, 4, NB), 256, 0, stream>>>(
        Wo, Oh, lsP, tsP, b_out, out, E, ticket, 18 * 4 * NB,
        out + (size_t)NB * NC * HW);
}